// Round 23
// baseline (182.029 us; speedup 1.0000x reference)
//
#include <hip/hip_runtime.h>
#include <hip/hip_bf16.h>
#include <math.h>

// Problem constants (from reference setup_inputs)
#define BB 32
#define NN 1024
#define DD 64
#define TT 2048
#define CHUNKS (TT / 256)   // 8 column-chunks of 256 (segsum geometry)
#define SEGS 16             // n-segments (decoupled scan)

typedef float f32x4 __attribute__((ext_vector_type(4)));
typedef unsigned short u16x4 __attribute__((ext_vector_type(4)));
using s16x8 = __attribute__((ext_vector_type(8))) short;   // 8 bf16 (4 VGPRs)

// alpha in LOG2 units: exp() becomes bare v_exp_f32. Validated R9+.
#define NLOG2E_HALF (-0.72134752044448169f)   // -0.5 * log2(e)

__device__ __forceinline__ float exp2_fast(float x) {
    return __builtin_amdgcn_exp2f(x);
}

// DPP move WITHOUT tied-old operand -> fuses into the consumer op.
template<int CTRL>
__device__ __forceinline__ float dpp_mov_f(float v) {
    return __int_as_float(
        __builtin_amdgcn_mov_dpp(__float_as_int(v), CTRL, 0xF, 0xF, true));
}

// Butterfly reduce over groups of 2^GB lanes (GB = 4, 5, or 6).
template<int GB>
__device__ __forceinline__ float groupMax(float v) {
    v = fmaxf(v, dpp_mov_f<0x0B1>(v));  // xor1
    v = fmaxf(v, dpp_mov_f<0x04E>(v));  // xor2
    v = fmaxf(v, dpp_mov_f<0x141>(v));  // xor4 (row_half_mirror)
    v = fmaxf(v, dpp_mov_f<0x140>(v));  // xor8 (row_mirror)
    if constexpr (GB >= 5) v = fmaxf(v, __shfl_xor(v, 16));
    if constexpr (GB >= 6) v = fmaxf(v, __shfl_xor(v, 32));
    return v;
}

template<int GB>
__device__ __forceinline__ float groupSum(float v) {
    v += dpp_mov_f<0x0B1>(v);
    v += dpp_mov_f<0x04E>(v);
    v += dpp_mov_f<0x141>(v);
    v += dpp_mov_f<0x140>(v);
    if constexpr (GB >= 5) v += __shfl_xor(v, 16);
    if constexpr (GB >= 6) v += __shfl_xor(v, 32);
    return v;
}

// bf16 round-to-nearest-even split: x ~= hi + lo, |x-hi-lo| <= 2^-18 |x|.
__device__ __forceinline__ unsigned short bf16_rne(float x) {
    unsigned u = __float_as_uint(x);
    return (unsigned short)((u + 0x7FFFu + ((u >> 16) & 1u)) >> 16);
}
__device__ __forceinline__ void bf16_split(float x, unsigned short& hi,
                                           unsigned short& lo) {
    const unsigned short h = bf16_rne(x);
    const float xh = __uint_as_float(((unsigned)h) << 16);
    hi = h;
    lo = bf16_rne(x - xh);
}

__device__ __forceinline__ void loadW(const float* __restrict__ W, int col,
                                      f32x4* wv) {
#pragma unroll
    for (int i = 0; i < 16; ++i) {
        wv[i].x = W[(size_t)(4 * i + 0) * TT + col];
        wv[i].y = W[(size_t)(4 * i + 1) * TT + col];
        wv[i].z = W[(size_t)(4 * i + 2) * TT + col];
        wv[i].w = W[(size_t)(4 * i + 3) * TT + col];
    }
}

__device__ __forceinline__ float hsum(f32x4 s) {
    return (s.x + s.y) + (s.z + s.w);
}

// Scalar dot4 (fallback only).
__device__ __forceinline__ void dot4(const float* __restrict__ x0p,
                                     const f32x4* wv, float* xw) {
    const f32x4* xr0 = (const f32x4*)(x0p);
    const f32x4* xr1 = (const f32x4*)(x0p + DD);
    const f32x4* xr2 = (const f32x4*)(x0p + 2 * DD);
    const f32x4* xr3 = (const f32x4*)(x0p + 3 * DD);
    f32x4 s0 = {0.f, 0.f, 0.f, 0.f};
    f32x4 s1 = {0.f, 0.f, 0.f, 0.f};
    f32x4 s2 = {0.f, 0.f, 0.f, 0.f};
    f32x4 s3 = {0.f, 0.f, 0.f, 0.f};
#pragma unroll
    for (int i = 0; i < 16; ++i) {
        const f32x4 w = wv[i];
        s0 += xr0[i] * w;
        s1 += xr1[i] * w;
        s2 += xr2[i] * w;
        s3 += xr3[i] * w;
    }
    xw[0] = hsum(s0); xw[1] = hsum(s1); xw[2] = hsum(s2); xw[3] = hsum(s3);
}

// ---------- fused precompute kernel ----------
// blocks [0, XB): data -> x_hi/x_lo bf16 [B][N][D], 4 elems/thread
// blocks [XB, XB+WB): W [D][T] -> W_hiT/W_loT bf16 [T][D], 1 elem/thread
#define XB ((BB * NN * DD) / (256 * 4))   // 2048
#define WB ((TT * DD) / 256)              // 512
__global__ __launch_bounds__(256)
void split_kernel(const float* __restrict__ x,
                  const float* __restrict__ W,
                  unsigned short* __restrict__ xh,
                  unsigned short* __restrict__ xl,
                  unsigned short* __restrict__ whT,
                  unsigned short* __restrict__ wlT)
{
    const int gid = blockIdx.x;
    if (gid < XB) {
        const int idx = (gid * 256 + threadIdx.x) * 4;
        const f32x4 v = *(const f32x4*)(x + idx);
        u16x4 h, lo;
#pragma unroll
        for (int j = 0; j < 4; ++j) {
            unsigned short hh, ll;
            bf16_split(v[j], hh, ll);
            h[j] = hh; lo[j] = ll;
        }
        *(u16x4*)(xh + idx) = h;
        *(u16x4*)(xl + idx) = lo;
    } else {
        const int idx = (gid - XB) * 256 + threadIdx.x;
        const int t = idx & (TT - 1);
        const int d = idx >> 11;
        unsigned short h, lo;
        bf16_split(W[(size_t)d * TT + t], h, lo);
        whT[(size_t)t * DD + d] = h;
        wlT[(size_t)t * DD + d] = lo;
    }
}

// ---------- pre-split fragment loads ----------

// B (W) fragments for a 64-col group from transposed bf16: one s16x8 load
// per fragment (layout: col = base + nt*16 + (l&15), k = ks*32+(l>>4)*8+j).
__device__ __forceinline__ void loadB64_pre(const unsigned short* __restrict__ whT,
                                            const unsigned short* __restrict__ wlT,
                                            int colbase, int l,
                                            s16x8 bh[2][4], s16x8 bl[2][4]) {
    const int c0 = colbase + (l & 15);
    const int kb = (l >> 4) * 8;
#pragma unroll
    for (int ks = 0; ks < 2; ++ks)
#pragma unroll
        for (int nt = 0; nt < 4; ++nt) {
            const size_t off = (size_t)(c0 + nt * 16) * DD + ks * 32 + kb;
            bh[ks][nt] = *(const s16x8*)(whT + off);
            bl[ks][nt] = *(const s16x8*)(wlT + off);
        }
}

// MFMA a 16-row x 64-col xw tile from pre-split bf16 x (3-product hi/lo).
__device__ __forceinline__ void mfma_tile16_pre(const unsigned short* __restrict__ xh,
                                                const unsigned short* __restrict__ xl,
                                                int tile_n0, int l,
                                                const s16x8 bh[2][4],
                                                const s16x8 bl[2][4],
                                                f32x4 acc[4]) {
#pragma unroll
    for (int nt = 0; nt < 4; ++nt) acc[nt] = (f32x4){0.f, 0.f, 0.f, 0.f};
    const int row = tile_n0 + (l & 15);
#pragma unroll
    for (int ks = 0; ks < 2; ++ks) {
        const size_t off = (size_t)row * DD + ks * 32 + (l >> 4) * 8;
        const s16x8 ah = *(const s16x8*)(xh + off);
        const s16x8 al = *(const s16x8*)(xl + off);
#pragma unroll
        for (int nt = 0; nt < 4; ++nt) {
            acc[nt] = __builtin_amdgcn_mfma_f32_16x16x32_bf16(ah, bh[ks][nt], acc[nt], 0, 0, 0);
            acc[nt] = __builtin_amdgcn_mfma_f32_16x16x32_bf16(ah, bl[ks][nt], acc[nt], 0, 0, 0);
            acc[nt] = __builtin_amdgcn_mfma_f32_16x16x32_bf16(al, bh[ks][nt], acc[nt], 0, 0, 0);
        }
    }
}

// Pass A (MFMA, pre-split inputs): per-(b, chunk256, segment) segsum.
template<int SEG>
__global__ __launch_bounds__(256)
void segsum_mfma_kernel(const unsigned short* __restrict__ xh,
                        const unsigned short* __restrict__ xl,
                        const unsigned short* __restrict__ whT,
                        const unsigned short* __restrict__ wlT,
                        const float* __restrict__ targets,
                        float* __restrict__ segsum)
{
    constexpr int NSEG = NN / SEG;            // 64
    __shared__ float ts[NSEG];

    const int blk   = blockIdx.x;
    const int s     = blk % SEG;
    const int rem   = blk / SEG;
    const int chunk = rem % CHUNKS;
    const int b     = rem / CHUNKS;
    const int tid   = threadIdx.x;
    const int wv    = tid >> 6;
    const int l     = tid & 63;

    const unsigned short* xbh = xh + (size_t)b * NN * DD;
    const unsigned short* xbl = xl + (size_t)b * NN * DD;
    const float* tb = targets + (size_t)b * NN;
    const int n0 = s * NSEG;

    if (tid < NSEG) ts[tid] = tb[n0 + tid];

    s16x8 bh[2][4], bl[2][4];
    loadB64_pre(whT, wlT, chunk * 256 + wv * 64, l, bh, bl);
    __syncthreads();

    float colacc[4] = {0.f, 0.f, 0.f, 0.f};

#pragma unroll 1
    for (int h = 0; h < NSEG / 16; ++h) {
        f32x4 acc[4];
        mfma_tile16_pre(xbh, xbl, n0 + h * 16, l, bh, bl, acc);
#pragma unroll
        for (int r = 0; r < 4; ++r) {
            const float tv = ts[h * 16 + (l >> 4) * 4 + r];
#pragma unroll
            for (int nt = 0; nt < 4; ++nt) {
                const float d = tv - acc[nt][r];
                colacc[nt] = fmaf(d * d, NLOG2E_HALF, colacc[nt]);
            }
        }
    }

#pragma unroll
    for (int nt = 0; nt < 4; ++nt) {
        colacc[nt] += __shfl_xor(colacc[nt], 16);
        colacc[nt] += __shfl_xor(colacc[nt], 32);
    }

    if (l < 16) {
        const size_t base = ((size_t)b * SEG + s) * TT + chunk * 256 + wv * 64 + l;
#pragma unroll
        for (int nt = 0; nt < 4; ++nt) segsum[base + nt * 16] = colacc[nt];
    }
}

// Pass B: 4-WAVE barrier-free MFMA scan. 256-thread block; wave wv owns
// col-group (cgq*4 + wv) of the same (b, segment). Each wave uses its own
// LDS quadrant -> no __syncthreads anywhere (R21's property), but 4 waves
// per workgroup slot -> ~4x the resident waves vs 1-wave blocks (R22's
// occupancy cap was the CU workgroup-slot limit, not LDS/VGPR).
// n is blockIdx-derived (uniform) -> targets stay on the scalar path.
template<int SEG, int GB>
__global__ __launch_bounds__(256)
void scan_mfma4_kernel(const unsigned short* __restrict__ xh,
                       const unsigned short* __restrict__ xl,
                       const unsigned short* __restrict__ whT,
                       const unsigned short* __restrict__ wlT,
                       const float* __restrict__ targets,
                       const float* __restrict__ segsum,
                       float* __restrict__ mP,
                       float* __restrict__ sP,
                       float* __restrict__ pP)
{
    constexpr int NSEG = NN / SEG;            // 64
    constexpr int MT   = 16;                  // points per tile
    constexpr int CGQ  = TT / 256;            // 8 col-quads
    constexpr int PPN  = TT >> GB;

    __shared__ __align__(16) float xw_tile[4][MT][68];   // 17.4 KB

    const int blk = blockIdx.x;
    const int s   = blk % SEG;
    const int rem = blk / SEG;
    const int cgq = rem % CGQ;
    const int b   = rem / CGQ;
    const int tid = threadIdx.x;
    const int wv  = tid >> 6;
    const int l   = tid & 63;
    const int cg  = cgq * 4 + wv;
    const int col = cg * 64 + l;

    const unsigned short* xbh = xh + (size_t)b * NN * DD;
    const unsigned short* xbl = xl + (size_t)b * NN * DD;
    const float* tb = targets + (size_t)b * NN;

    s16x8 bh[2][4], bl[2][4];
    loadB64_pre(whT, wlT, cg * 64, l, bh, bl);

    const int  k16    = col >> GB;
    const bool writer = (l & ((1 << GB) - 1)) == 0;
    const size_t base0 = (size_t)b * NN * PPN + k16;

    // exclusive segment prefix (log2 units)
    float alpha = 0.0f;
    if constexpr (SEG > 1) {
        for (int s2 = 0; s2 < s; ++s2)
            alpha += segsum[((size_t)b * SEG + s2) * TT + col];
    }

    const int n0 = s * NSEG;

#pragma unroll 1
    for (int h = 0; h < NSEG / MT; ++h) {
        f32x4 acc[4];
        mfma_tile16_pre(xbh, xbl, n0 + h * MT, l, bh, bl, acc);

        // C -> wave-private LDS quadrant (row = (l>>4)*4+r, col = nt*16+(l&15))
#pragma unroll
        for (int nt = 0; nt < 4; ++nt)
#pragma unroll
            for (int r = 0; r < 4; ++r)
                xw_tile[wv][(l >> 4) * 4 + r][nt * 16 + (l & 15)] = acc[nt][r];

#pragma unroll 1
        for (int q = 0; q < MT; q += 4) {
            const int n = n0 + h * MT + q;
            float xw[4];
#pragma unroll
            for (int j = 0; j < 4; ++j) xw[j] = xw_tile[wv][q + j][l];

            float a[4];
            float al_ = alpha;
#pragma unroll
            for (int j = 0; j < 4; ++j) {
                a[j] = al_;
                const float d = tb[n + j] - xw[j];
                al_ = fmaf(d * d, NLOG2E_HALF, al_);
            }
            alpha = al_;

            float m[4], e[4], qv[4], sv[4], pv[4];
#pragma unroll
            for (int j = 0; j < 4; ++j) m[j] = groupMax<GB>(a[j]);
#pragma unroll
            for (int j = 0; j < 4; ++j) {
                e[j]  = exp2_fast(a[j] - m[j]);
                qv[j] = e[j] * xw[j];
            }
#pragma unroll
            for (int j = 0; j < 4; ++j) sv[j] = groupSum<GB>(e[j]);
#pragma unroll
            for (int j = 0; j < 4; ++j) pv[j] = groupSum<GB>(qv[j]);

            if (writer) {
                const size_t i0 = base0 + (size_t)n * PPN;
#pragma unroll
                for (int j = 0; j < 4; ++j) {
                    mP[i0 + (size_t)j * PPN] = m[j];
                    sP[i0 + (size_t)j * PPN] = sv[j];
                    pP[i0 + (size_t)j * PPN] = pv[j];
                }
            }
        }
        // no barrier: each wave's LDS quadrant is private; within-wave LDS
        // ops are program-ordered (compiler inserts lgkmcnt waits).
    }
}

// Single-stream scalar scan (fallback path only; R14 form).
template<int SEG, int GB>
__global__ __launch_bounds__(256, 4)
void scan_kernel(const float* __restrict__ data,
                 const float* __restrict__ targets,
                 const float* __restrict__ W,
                 const float* __restrict__ segsum,
                 float* __restrict__ mP,
                 float* __restrict__ sP,
                 float* __restrict__ pP)
{
    constexpr int NSEG = NN / SEG;
    constexpr int PPN  = TT >> GB;
    const int blk   = blockIdx.x;
    const int s     = blk % SEG;
    const int rem   = blk / SEG;
    const int chunk = rem % CHUNKS;
    const int b     = rem / CHUNKS;
    const int tid   = threadIdx.x;
    const int lane  = tid & 63;
    const int col   = chunk * 256 + tid;

    f32x4 wv[16];
    loadW(W, col, wv);

    const float* xb = data + (size_t)b * NN * DD;
    const float* tb = targets + (size_t)b * NN;

    const int  k      = (chunk * 256 + (tid & ~((1 << GB) - 1))) >> GB;
    const bool writer = (lane & ((1 << GB) - 1)) == 0;
    const size_t base0 = (size_t)b * NN * PPN + k;

    float alpha = 0.0f;
    if constexpr (SEG > 1) {
        for (int s2 = 0; s2 < s; ++s2)
            alpha += segsum[((size_t)b * SEG + s2) * TT + col];
    }

    const int n0 = s * NSEG;
    for (int n = n0; n < n0 + NSEG; n += 4) {
        float xw[4];
        dot4(xb + (size_t)n * DD, wv, xw);
        float a[4];
        float al = alpha;
#pragma unroll
        for (int j = 0; j < 4; ++j) {
            a[j] = al;
            const float d = tb[n + j] - xw[j];
            al = fmaf(d * d, NLOG2E_HALF, al);
        }
        alpha = al;
        float m[4], e[4], qv[4], sv[4], pv[4];
#pragma unroll
        for (int j = 0; j < 4; ++j) m[j] = groupMax<GB>(a[j]);
#pragma unroll
        for (int j = 0; j < 4; ++j) {
            e[j]  = exp2_fast(a[j] - m[j]);
            qv[j] = e[j] * xw[j];
        }
#pragma unroll
        for (int j = 0; j < 4; ++j) sv[j] = groupSum<GB>(e[j]);
#pragma unroll
        for (int j = 0; j < 4; ++j) pv[j] = groupSum<GB>(qv[j]);
        if (writer) {
            const size_t i0 = base0 + (size_t)n * PPN;
#pragma unroll
            for (int j = 0; j < 4; ++j) {
                mP[i0 + (size_t)j * PPN] = m[j];
                sP[i0 + (size_t)j * PPN] = sv[j];
                pP[i0 + (size_t)j * PPN] = pv[j];
            }
        }
    }
}

// Pass C: one wave per (b,n): merge PPN partials (log2 units).
template<int PPN>
__global__ __launch_bounds__(256)
void combine_kernel(const float* __restrict__ mP,
                    const float* __restrict__ sP,
                    const float* __restrict__ pP,
                    float* __restrict__ out)
{
    const int wgid = blockIdx.x * 4 + (threadIdx.x >> 6);   // = b*NN + n
    const int lane = threadIdx.x & 63;
    const size_t base = (size_t)wgid * PPN;

    float m = -INFINITY, s = 0.0f, p = 0.0f;
    if constexpr (PPN >= 64) {
#pragma unroll
        for (int j = 0; j < PPN / 64; ++j) {
            const size_t idx = base + lane + j * 64;
            const float mk = mP[idx], sk = sP[idx], pk = pP[idx];
            const float M  = fmaxf(m, mk);
            const float e1 = exp2_fast(m - M), e2 = exp2_fast(mk - M);
            s = s * e1 + sk * e2;
            p = p * e1 + pk * e2;
            m = M;
        }
    } else {
        if (lane < PPN) {
            m = mP[base + lane]; s = sP[base + lane]; p = pP[base + lane];
        }
    }

#pragma unroll
    for (int off = 1; off < 64; off <<= 1) {
        const float mo = __shfl_xor(m, off);
        const float so = __shfl_xor(s, off);
        const float po = __shfl_xor(p, off);
        const float M  = fmaxf(m, mo);
        const float e1 = exp2_fast(m - M), e2 = exp2_fast(mo - M);
        s = s * e1 + so * e2;
        p = p * e1 + po * e2;
        m = M;
    }

    if (lane == 0) out[wgid] = p / s;
}

extern "C" void kernel_launch(void* const* d_in, const int* in_sizes, int n_in,
                              void* d_out, int out_size, void* d_ws, size_t ws_size,
                              hipStream_t stream)
{
    (void)in_sizes; (void)n_in; (void)out_size;
    const float* data    = (const float*)d_in[0];
    const float* targets = (const float*)d_in[1];
    const float* W       = (const float*)d_in[2];
    float* out = (float*)d_out;

    const size_t plane4 = (size_t)BB * NN * (TT >> 4);   // 4.19M floats
    const size_t plane5 = (size_t)BB * NN * (TT >> 5);
    const size_t plane6 = (size_t)BB * NN * (TT >> 6);
    const size_t seg16  = (size_t)BB * SEGS * TT;
    const size_t xsplitF = (size_t)BB * NN * DD / 2;     // ushort arrays in float units
    const size_t wsplitF = (size_t)TT * DD / 2;

    const int seg_grid  = BB * SEGS * CHUNKS;            // 4096 blocks of 256
    const int scan_grid = BB * (TT / 256) * SEGS;        // 4096 blocks of 256

    auto launch_pre = [&](size_t plane, auto gbTag) {
        float* mP = (float*)d_ws;
        float* sP = mP + plane;
        float* pP = sP + plane;
        float* sg = pP + plane;
        unsigned short* xh  = (unsigned short*)(sg + seg16);
        unsigned short* xl  = xh + (size_t)BB * NN * DD;
        unsigned short* whT = xl + (size_t)BB * NN * DD;
        unsigned short* wlT = whT + (size_t)TT * DD;

        split_kernel<<<XB + WB, 256, 0, stream>>>(data, W, xh, xl, whT, wlT);
        segsum_mfma_kernel<SEGS><<<seg_grid, 256, 0, stream>>>(xh, xl, whT, wlT, targets, sg);
        constexpr int GBv = decltype(gbTag)::value;
        scan_mfma4_kernel<SEGS, GBv><<<scan_grid, 256, 0, stream>>>(xh, xl, whT, wlT, targets, sg, mP, sP, pP);
        combine_kernel<(TT >> GBv)><<<(BB * NN) / 4, 256, 0, stream>>>(mP, sP, pP, out);
    };

    const size_t need4 = (3 * plane4 + seg16 + 2 * xsplitF + 2 * wsplitF) * sizeof(float);
    const size_t need5 = (3 * plane5 + seg16 + 2 * xsplitF + 2 * wsplitF) * sizeof(float);
    const size_t need6 = (3 * plane6 + seg16 + 2 * xsplitF + 2 * wsplitF) * sizeof(float);

    if (ws_size >= need4) {
        launch_pre(plane4, std::integral_constant<int, 4>{});
    } else if (ws_size >= need5) {
        launch_pre(plane5, std::integral_constant<int, 5>{});
    } else if (ws_size >= need6) {
        launch_pre(plane6, std::integral_constant<int, 6>{});
    } else {
        // minimal fallback: scalar single-segment scan (slow but correct)
        float* mP = (float*)d_ws;
        float* sP = mP + plane6;
        float* pP = sP + plane6;
        scan_kernel<1, 6><<<BB * CHUNKS, 256, 0, stream>>>(data, targets, W, nullptr, mP, sP, pP);
        combine_kernel<32><<<(BB * NN) / 4, 256, 0, stream>>>(mP, sP, pP, out);
    }
}

// Round 24
// 173.108 us; speedup vs baseline: 1.0515x; 1.0515x over previous
//
#include <hip/hip_runtime.h>
#include <hip/hip_bf16.h>
#include <math.h>

// Problem constants (from reference setup_inputs)
#define BB 32
#define NN 1024
#define DD 64
#define TT 2048
#define CHUNKS (TT / 256)   // 8 column-chunks of 256 (segsum geometry)
#define SEGS 16             // n-segments (decoupled scan)

typedef float f32x4 __attribute__((ext_vector_type(4)));
using s16x8 = __attribute__((ext_vector_type(8))) short;   // 8 bf16 (4 VGPRs)

// alpha in LOG2 units: exp() becomes bare v_exp_f32. Validated R9+.
#define NLOG2E_HALF (-0.72134752044448169f)   // -0.5 * log2(e)

__device__ __forceinline__ float exp2_fast(float x) {
    return __builtin_amdgcn_exp2f(x);
}

// DPP move WITHOUT tied-old operand -> fuses into the consumer op.
template<int CTRL>
__device__ __forceinline__ float dpp_mov_f(float v) {
    return __int_as_float(
        __builtin_amdgcn_mov_dpp(__float_as_int(v), CTRL, 0xF, 0xF, true));
}

// Butterfly reduce over groups of 2^GB lanes (GB = 4, 5, or 6).
template<int GB>
__device__ __forceinline__ float groupMax(float v) {
    v = fmaxf(v, dpp_mov_f<0x0B1>(v));  // xor1
    v = fmaxf(v, dpp_mov_f<0x04E>(v));  // xor2
    v = fmaxf(v, dpp_mov_f<0x141>(v));  // xor4 (row_half_mirror)
    v = fmaxf(v, dpp_mov_f<0x140>(v));  // xor8 (row_mirror)
    if constexpr (GB >= 5) v = fmaxf(v, __shfl_xor(v, 16));
    if constexpr (GB >= 6) v = fmaxf(v, __shfl_xor(v, 32));
    return v;
}

template<int GB>
__device__ __forceinline__ float groupSum(float v) {
    v += dpp_mov_f<0x0B1>(v);
    v += dpp_mov_f<0x04E>(v);
    v += dpp_mov_f<0x141>(v);
    v += dpp_mov_f<0x140>(v);
    if constexpr (GB >= 5) v += __shfl_xor(v, 16);
    if constexpr (GB >= 6) v += __shfl_xor(v, 32);
    return v;
}

// bf16 round-to-nearest-even split: x ~= hi + lo, |x-hi-lo| <= 2^-18 |x|.
__device__ __forceinline__ unsigned short bf16_rne(float x) {
    unsigned u = __float_as_uint(x);
    return (unsigned short)((u + 0x7FFFu + ((u >> 16) & 1u)) >> 16);
}
__device__ __forceinline__ void bf16_split(float x, unsigned short& hi,
                                           unsigned short& lo) {
    const unsigned short h = bf16_rne(x);
    const float xh = __uint_as_float(((unsigned)h) << 16);
    hi = h;
    lo = bf16_rne(x - xh);
}

__device__ __forceinline__ void loadW(const float* __restrict__ W, int col,
                                      f32x4* wv) {
#pragma unroll
    for (int i = 0; i < 16; ++i) {
        wv[i].x = W[(size_t)(4 * i + 0) * TT + col];
        wv[i].y = W[(size_t)(4 * i + 1) * TT + col];
        wv[i].z = W[(size_t)(4 * i + 2) * TT + col];
        wv[i].w = W[(size_t)(4 * i + 3) * TT + col];
    }
}

__device__ __forceinline__ float hsum(f32x4 s) {
    return (s.x + s.y) + (s.z + s.w);
}

// Scalar dot4 (fallback only).
__device__ __forceinline__ void dot4(const float* __restrict__ x0p,
                                     const f32x4* wv, float* xw) {
    const f32x4* xr0 = (const f32x4*)(x0p);
    const f32x4* xr1 = (const f32x4*)(x0p + DD);
    const f32x4* xr2 = (const f32x4*)(x0p + 2 * DD);
    const f32x4* xr3 = (const f32x4*)(x0p + 3 * DD);
    f32x4 s0 = {0.f, 0.f, 0.f, 0.f};
    f32x4 s1 = {0.f, 0.f, 0.f, 0.f};
    f32x4 s2 = {0.f, 0.f, 0.f, 0.f};
    f32x4 s3 = {0.f, 0.f, 0.f, 0.f};
#pragma unroll
    for (int i = 0; i < 16; ++i) {
        const f32x4 w = wv[i];
        s0 += xr0[i] * w;
        s1 += xr1[i] * w;
        s2 += xr2[i] * w;
        s3 += xr3[i] * w;
    }
    xw[0] = hsum(s0); xw[1] = hsum(s1); xw[2] = hsum(s2); xw[3] = hsum(s3);
}

// ---------- split-producing fragment builders (segsum) ----------

// B (W) fragments from f32 W with inline split; optionally store the split
// fragments to whT/wlT [T][D] (contiguous 16B per store, data in registers).
__device__ __forceinline__ void loadB64_split(const float* __restrict__ W,
                                              int colbase, int l,
                                              s16x8 bh[2][4], s16x8 bl[2][4],
                                              bool storeW,
                                              unsigned short* __restrict__ whT,
                                              unsigned short* __restrict__ wlT) {
    const int c0  = colbase + (l & 15);
    const int kb0 = (l >> 4) * 8;
#pragma unroll
    for (int ks = 0; ks < 2; ++ks)
#pragma unroll
        for (int nt = 0; nt < 4; ++nt) {
            const int cw = c0 + nt * 16;
#pragma unroll
            for (int j = 0; j < 8; ++j) {
                unsigned short h, lo_;
                bf16_split(W[(size_t)(ks * 32 + kb0 + j) * TT + cw], h, lo_);
                bh[ks][nt][j] = (short)h;
                bl[ks][nt][j] = (short)lo_;
            }
            if (storeW) {
                const size_t off = (size_t)cw * DD + ks * 32 + kb0;
                *(s16x8*)(whT + off) = bh[ks][nt];
                *(s16x8*)(wlT + off) = bl[ks][nt];
            }
        }
}

// MFMA 16x64 tile from f32 x with inline split; optionally store the split
// A-fragments to xh/xl [N][D] for this batch (each (row,d) covered once).
__device__ __forceinline__ void mfma_tile16_split(const float* __restrict__ xb,
                                                  int tile_n0, int l,
                                                  const s16x8 bh[2][4],
                                                  const s16x8 bl[2][4],
                                                  f32x4 acc[4],
                                                  bool storeX,
                                                  unsigned short* __restrict__ xhB,
                                                  unsigned short* __restrict__ xlB) {
#pragma unroll
    for (int nt = 0; nt < 4; ++nt) acc[nt] = (f32x4){0.f, 0.f, 0.f, 0.f};
    const int row = tile_n0 + (l & 15);
#pragma unroll
    for (int ks = 0; ks < 2; ++ks) {
        const int kb = ks * 32 + (l >> 4) * 8;
        s16x8 ah, al;
#pragma unroll
        for (int j = 0; j < 8; ++j) {
            unsigned short hh, ll;
            bf16_split(xb[(size_t)row * DD + kb + j], hh, ll);
            ah[j] = (short)hh; al[j] = (short)ll;
        }
        if (storeX) {
            const size_t off = (size_t)row * DD + kb;
            *(s16x8*)(xhB + off) = ah;
            *(s16x8*)(xlB + off) = al;
        }
#pragma unroll
        for (int nt = 0; nt < 4; ++nt) {
            acc[nt] = __builtin_amdgcn_mfma_f32_16x16x32_bf16(ah, bh[ks][nt], acc[nt], 0, 0, 0);
            acc[nt] = __builtin_amdgcn_mfma_f32_16x16x32_bf16(ah, bl[ks][nt], acc[nt], 0, 0, 0);
            acc[nt] = __builtin_amdgcn_mfma_f32_16x16x32_bf16(al, bh[ks][nt], acc[nt], 0, 0, 0);
        }
    }
}

// ---------- pre-split fragment loads (scan) ----------

__device__ __forceinline__ void loadB64_pre(const unsigned short* __restrict__ whT,
                                            const unsigned short* __restrict__ wlT,
                                            int colbase, int l,
                                            s16x8 bh[2][4], s16x8 bl[2][4]) {
    const int c0 = colbase + (l & 15);
    const int kb = (l >> 4) * 8;
#pragma unroll
    for (int ks = 0; ks < 2; ++ks)
#pragma unroll
        for (int nt = 0; nt < 4; ++nt) {
            const size_t off = (size_t)(c0 + nt * 16) * DD + ks * 32 + kb;
            bh[ks][nt] = *(const s16x8*)(whT + off);
            bl[ks][nt] = *(const s16x8*)(wlT + off);
        }
}

__device__ __forceinline__ void mfma_tile16_pre(const unsigned short* __restrict__ xh,
                                                const unsigned short* __restrict__ xl,
                                                int tile_n0, int l,
                                                const s16x8 bh[2][4],
                                                const s16x8 bl[2][4],
                                                f32x4 acc[4]) {
#pragma unroll
    for (int nt = 0; nt < 4; ++nt) acc[nt] = (f32x4){0.f, 0.f, 0.f, 0.f};
    const int row = tile_n0 + (l & 15);
#pragma unroll
    for (int ks = 0; ks < 2; ++ks) {
        const size_t off = (size_t)row * DD + ks * 32 + (l >> 4) * 8;
        const s16x8 ah = *(const s16x8*)(xh + off);
        const s16x8 al = *(const s16x8*)(xl + off);
#pragma unroll
        for (int nt = 0; nt < 4; ++nt) {
            acc[nt] = __builtin_amdgcn_mfma_f32_16x16x32_bf16(ah, bh[ks][nt], acc[nt], 0, 0, 0);
            acc[nt] = __builtin_amdgcn_mfma_f32_16x16x32_bf16(ah, bl[ks][nt], acc[nt], 0, 0, 0);
            acc[nt] = __builtin_amdgcn_mfma_f32_16x16x32_bf16(al, bh[ks][nt], acc[nt], 0, 0, 0);
        }
    }
}

// Pass A: MFMA segsum (inline splits) + side-effect split stores.
// chunk==0 & wave==0 blocks store x splits (cover all (b, n, d) once);
// b==0 & s==0 blocks store W splits (all 4 waves: distinct cols).
template<int SEG>
__global__ __launch_bounds__(256)
void segsum_mfma_kernel(const float* __restrict__ data,
                        const float* __restrict__ W,
                        const float* __restrict__ targets,
                        float* __restrict__ segsum,
                        unsigned short* __restrict__ xh,
                        unsigned short* __restrict__ xl,
                        unsigned short* __restrict__ whT,
                        unsigned short* __restrict__ wlT)
{
    constexpr int NSEG = NN / SEG;            // 64
    __shared__ float ts[NSEG];

    const int blk   = blockIdx.x;
    const int s     = blk % SEG;
    const int rem   = blk / SEG;
    const int chunk = rem % CHUNKS;
    const int b     = rem / CHUNKS;
    const int tid   = threadIdx.x;
    const int wv    = tid >> 6;
    const int l     = tid & 63;

    const float* xb = data + (size_t)b * NN * DD;
    const float* tb = targets + (size_t)b * NN;
    const int n0 = s * NSEG;

    if (tid < NSEG) ts[tid] = tb[n0 + tid];

    const bool storeW = (b == 0) && (s == 0);
    const bool storeX = (chunk == 0) && (wv == 0);
    unsigned short* xhB = xh + (size_t)b * NN * DD;
    unsigned short* xlB = xl + (size_t)b * NN * DD;

    s16x8 bh[2][4], bl[2][4];
    loadB64_split(W, chunk * 256 + wv * 64, l, bh, bl, storeW, whT, wlT);
    __syncthreads();

    float colacc[4] = {0.f, 0.f, 0.f, 0.f};

#pragma unroll 1
    for (int h = 0; h < NSEG / 16; ++h) {
        f32x4 acc[4];
        mfma_tile16_split(xb, n0 + h * 16, l, bh, bl, acc, storeX, xhB, xlB);
#pragma unroll
        for (int r = 0; r < 4; ++r) {
            const float tv = ts[h * 16 + (l >> 4) * 4 + r];
#pragma unroll
            for (int nt = 0; nt < 4; ++nt) {
                const float d = tv - acc[nt][r];
                colacc[nt] = fmaf(d * d, NLOG2E_HALF, colacc[nt]);
            }
        }
    }

#pragma unroll
    for (int nt = 0; nt < 4; ++nt) {
        colacc[nt] += __shfl_xor(colacc[nt], 16);
        colacc[nt] += __shfl_xor(colacc[nt], 32);
    }

    if (l < 16) {
        const size_t base = ((size_t)b * SEG + s) * TT + chunk * 256 + wv * 64 + l;
#pragma unroll
        for (int nt = 0; nt < 4; ++nt) segsum[base + nt * 16] = colacc[nt];
    }
}

// Pass B: DUAL-STREAM one-wave MFMA scan, barrier-free, pre-split inputs.
// Each 64-thread block owns (b, 64-col group, segment-pair sA/sA+HALF).
// Per tile: MFMA A -> write A -> issue MFMA B -> softmax A (B's matrix
// latency hides under A's VALU; separate pipes) -> write B -> softmax B.
template<int SEG, int GB>
__global__ __launch_bounds__(64)
void scan2_mfma_kernel(const unsigned short* __restrict__ xh,
                       const unsigned short* __restrict__ xl,
                       const unsigned short* __restrict__ whT,
                       const unsigned short* __restrict__ wlT,
                       const float* __restrict__ targets,
                       const float* __restrict__ segsum,
                       float* __restrict__ mP,
                       float* __restrict__ sP,
                       float* __restrict__ pP)
{
    constexpr int NSEG = NN / SEG;            // 64
    constexpr int MT   = 16;
    constexpr int HALF = SEG / 2;             // 8
    constexpr int CG   = TT / 64;             // 32
    constexpr int PPN  = TT >> GB;

    __shared__ __align__(16) float xwA[MT][68];
    __shared__ __align__(16) float xwB[MT][68];

    const int blk = blockIdx.x;
    const int sA  = blk % HALF;
    const int rem = blk / HALF;
    const int cg  = rem % CG;
    const int b   = rem / CG;
    const int sB  = sA + HALF;
    const int l   = threadIdx.x;
    const int col = cg * 64 + l;

    const unsigned short* xbh = xh + (size_t)b * NN * DD;
    const unsigned short* xbl = xl + (size_t)b * NN * DD;
    const float* tb = targets + (size_t)b * NN;

    s16x8 bh[2][4], bl[2][4];
    loadB64_pre(whT, wlT, cg * 64, l, bh, bl);

    const int  k16    = col >> GB;
    const bool writer = (l & ((1 << GB) - 1)) == 0;
    const size_t base0 = (size_t)b * NN * PPN + k16;

    // exclusive segment prefixes for both streams (log2 units)
    float alphaA = 0.0f, alphaB = 0.0f;
    for (int s2 = 0; s2 < sB; ++s2) {
        const float v = segsum[((size_t)b * SEG + s2) * TT + col];
        alphaB += v;
        if (s2 < sA) alphaA += v;
    }

    const int nA0 = sA * NSEG;
    const int nB0 = sB * NSEG;

    // softmax+emit for 16 points of one stream from one LDS tile.
    auto softmax16 = [&](float& alpha, int nbase, const float (*tile)[68]) {
#pragma unroll 1
        for (int q = 0; q < MT; q += 4) {
            const int n = nbase + q;
            float xw[4];
#pragma unroll
            for (int j = 0; j < 4; ++j) xw[j] = tile[q + j][l];

            float a[4];
            float al_ = alpha;
#pragma unroll
            for (int j = 0; j < 4; ++j) {
                a[j] = al_;
                const float d = tb[n + j] - xw[j];
                al_ = fmaf(d * d, NLOG2E_HALF, al_);
            }
            alpha = al_;

            float m[4], e[4], qv[4], sv[4], pv[4];
#pragma unroll
            for (int j = 0; j < 4; ++j) m[j] = groupMax<GB>(a[j]);
#pragma unroll
            for (int j = 0; j < 4; ++j) {
                e[j]  = exp2_fast(a[j] - m[j]);
                qv[j] = e[j] * xw[j];
            }
#pragma unroll
            for (int j = 0; j < 4; ++j) sv[j] = groupSum<GB>(e[j]);
#pragma unroll
            for (int j = 0; j < 4; ++j) pv[j] = groupSum<GB>(qv[j]);

            if (writer) {
                const size_t i0 = base0 + (size_t)n * PPN;
#pragma unroll
                for (int j = 0; j < 4; ++j) {
                    mP[i0 + (size_t)j * PPN] = m[j];
                    sP[i0 + (size_t)j * PPN] = sv[j];
                    pP[i0 + (size_t)j * PPN] = pv[j];
                }
            }
        }
    };

#pragma unroll 1
    for (int h = 0; h < NSEG / MT; ++h) {
        f32x4 accA[4];
        mfma_tile16_pre(xbh, xbl, nA0 + h * MT, l, bh, bl, accA);
#pragma unroll
        for (int nt = 0; nt < 4; ++nt)
#pragma unroll
            for (int r = 0; r < 4; ++r)
                xwA[(l >> 4) * 4 + r][nt * 16 + (l & 15)] = accA[nt][r];

        f32x4 accB[4];
        mfma_tile16_pre(xbh, xbl, nB0 + h * MT, l, bh, bl, accB);  // overlaps softmax A

        softmax16(alphaA, nA0 + h * MT, xwA);

#pragma unroll
        for (int nt = 0; nt < 4; ++nt)
#pragma unroll
            for (int r = 0; r < 4; ++r)
                xwB[(l >> 4) * 4 + r][nt * 16 + (l & 15)] = accB[nt][r];

        softmax16(alphaB, nB0 + h * MT, xwB);
        // no barriers: single wave, LDS ops program-ordered.
    }
}

// Single-stream scalar scan (fallback path only; R14 form).
template<int SEG, int GB>
__global__ __launch_bounds__(256, 4)
void scan_kernel(const float* __restrict__ data,
                 const float* __restrict__ targets,
                 const float* __restrict__ W,
                 const float* __restrict__ segsum,
                 float* __restrict__ mP,
                 float* __restrict__ sP,
                 float* __restrict__ pP)
{
    constexpr int NSEG = NN / SEG;
    constexpr int PPN  = TT >> GB;
    const int blk   = blockIdx.x;
    const int s     = blk % SEG;
    const int rem   = blk / SEG;
    const int chunk = rem % CHUNKS;
    const int b     = rem / CHUNKS;
    const int tid   = threadIdx.x;
    const int lane  = tid & 63;
    const int col   = chunk * 256 + tid;

    f32x4 wv[16];
    loadW(W, col, wv);

    const float* xb = data + (size_t)b * NN * DD;
    const float* tb = targets + (size_t)b * NN;

    const int  k      = (chunk * 256 + (tid & ~((1 << GB) - 1))) >> GB;
    const bool writer = (lane & ((1 << GB) - 1)) == 0;
    const size_t base0 = (size_t)b * NN * PPN + k;

    float alpha = 0.0f;
    if constexpr (SEG > 1) {
        for (int s2 = 0; s2 < s; ++s2)
            alpha += segsum[((size_t)b * SEG + s2) * TT + col];
    }

    const int n0 = s * NSEG;
    for (int n = n0; n < n0 + NSEG; n += 4) {
        float xw[4];
        dot4(xb + (size_t)n * DD, wv, xw);
        float a[4];
        float al = alpha;
#pragma unroll
        for (int j = 0; j < 4; ++j) {
            a[j] = al;
            const float d = tb[n + j] - xw[j];
            al = fmaf(d * d, NLOG2E_HALF, al);
        }
        alpha = al;
        float m[4], e[4], qv[4], sv[4], pv[4];
#pragma unroll
        for (int j = 0; j < 4; ++j) m[j] = groupMax<GB>(a[j]);
#pragma unroll
        for (int j = 0; j < 4; ++j) {
            e[j]  = exp2_fast(a[j] - m[j]);
            qv[j] = e[j] * xw[j];
        }
#pragma unroll
        for (int j = 0; j < 4; ++j) sv[j] = groupSum<GB>(e[j]);
#pragma unroll
        for (int j = 0; j < 4; ++j) pv[j] = groupSum<GB>(qv[j]);
        if (writer) {
            const size_t i0 = base0 + (size_t)n * PPN;
#pragma unroll
            for (int j = 0; j < 4; ++j) {
                mP[i0 + (size_t)j * PPN] = m[j];
                sP[i0 + (size_t)j * PPN] = sv[j];
                pP[i0 + (size_t)j * PPN] = pv[j];
            }
        }
    }
}

// Pass C: one wave per (b,n): merge PPN partials (log2 units).
template<int PPN>
__global__ __launch_bounds__(256)
void combine_kernel(const float* __restrict__ mP,
                    const float* __restrict__ sP,
                    const float* __restrict__ pP,
                    float* __restrict__ out)
{
    const int wgid = blockIdx.x * 4 + (threadIdx.x >> 6);   // = b*NN + n
    const int lane = threadIdx.x & 63;
    const size_t base = (size_t)wgid * PPN;

    float m = -INFINITY, s = 0.0f, p = 0.0f;
    if constexpr (PPN >= 64) {
#pragma unroll
        for (int j = 0; j < PPN / 64; ++j) {
            const size_t idx = base + lane + j * 64;
            const float mk = mP[idx], sk = sP[idx], pk = pP[idx];
            const float M  = fmaxf(m, mk);
            const float e1 = exp2_fast(m - M), e2 = exp2_fast(mk - M);
            s = s * e1 + sk * e2;
            p = p * e1 + pk * e2;
            m = M;
        }
    } else {
        if (lane < PPN) {
            m = mP[base + lane]; s = sP[base + lane]; p = pP[base + lane];
        }
    }

#pragma unroll
    for (int off = 1; off < 64; off <<= 1) {
        const float mo = __shfl_xor(m, off);
        const float so = __shfl_xor(s, off);
        const float po = __shfl_xor(p, off);
        const float M  = fmaxf(m, mo);
        const float e1 = exp2_fast(m - M), e2 = exp2_fast(mo - M);
        s = s * e1 + so * e2;
        p = p * e1 + po * e2;
        m = M;
    }

    if (lane == 0) out[wgid] = p / s;
}

extern "C" void kernel_launch(void* const* d_in, const int* in_sizes, int n_in,
                              void* d_out, int out_size, void* d_ws, size_t ws_size,
                              hipStream_t stream)
{
    (void)in_sizes; (void)n_in; (void)out_size;
    const float* data    = (const float*)d_in[0];
    const float* targets = (const float*)d_in[1];
    const float* W       = (const float*)d_in[2];
    float* out = (float*)d_out;

    const size_t plane4 = (size_t)BB * NN * (TT >> 4);
    const size_t plane5 = (size_t)BB * NN * (TT >> 5);
    const size_t plane6 = (size_t)BB * NN * (TT >> 6);
    const size_t seg16  = (size_t)BB * SEGS * TT;
    const size_t xsplitF = (size_t)BB * NN * DD / 2;     // ushort arrays in float units
    const size_t wsplitF = (size_t)TT * DD / 2;

    const int seg_grid   = BB * SEGS * CHUNKS;           // 4096 blocks of 256
    const int scan2_grid = BB * (TT / 64) * (SEGS / 2);  // 8192 blocks of 64

    auto launch_pre = [&](size_t plane, auto gbTag) {
        float* mP = (float*)d_ws;
        float* sP = mP + plane;
        float* pP = sP + plane;
        float* sg = pP + plane;
        unsigned short* xh  = (unsigned short*)(sg + seg16);
        unsigned short* xl  = xh + (size_t)BB * NN * DD;
        unsigned short* whT = xl + (size_t)BB * NN * DD;
        unsigned short* wlT = whT + (size_t)TT * DD;

        segsum_mfma_kernel<SEGS><<<seg_grid, 256, 0, stream>>>(
            data, W, targets, sg, xh, xl, whT, wlT);
        constexpr int GBv = decltype(gbTag)::value;
        scan2_mfma_kernel<SEGS, GBv><<<scan2_grid, 64, 0, stream>>>(
            xh, xl, whT, wlT, targets, sg, mP, sP, pP);
        combine_kernel<(TT >> GBv)><<<(BB * NN) / 4, 256, 0, stream>>>(mP, sP, pP, out);
    };

    const size_t need4 = (3 * plane4 + seg16 + 2 * xsplitF + 2 * wsplitF) * sizeof(float);
    const size_t need5 = (3 * plane5 + seg16 + 2 * xsplitF + 2 * wsplitF) * sizeof(float);
    const size_t need6 = (3 * plane6 + seg16 + 2 * xsplitF + 2 * wsplitF) * sizeof(float);

    if (ws_size >= need4) {
        launch_pre(plane4, std::integral_constant<int, 4>{});
    } else if (ws_size >= need5) {
        launch_pre(plane5, std::integral_constant<int, 5>{});
    } else if (ws_size >= need6) {
        launch_pre(plane6, std::integral_constant<int, 6>{});
    } else {
        // minimal fallback: scalar single-segment scan (slow but correct)
        float* mP = (float*)d_ws;
        float* sP = mP + plane6;
        float* pP = sP + plane6;
        scan_kernel<1, 6><<<BB * CHUNKS, 256, 0, stream>>>(data, targets, W, nullptr, mP, sP, pP);
        combine_kernel<32><<<(BB * NN) / 4, 256, 0, stream>>>(mP, sP, pP, out);
    }
}

// Round 25
// 168.887 us; speedup vs baseline: 1.0778x; 1.0250x over previous
//
#include <hip/hip_runtime.h>
#include <hip/hip_bf16.h>
#include <math.h>

// Problem constants (from reference setup_inputs)
#define BB 32
#define NN 1024
#define DD 64
#define TT 2048
#define CHUNKS (TT / 256)   // 8 column-chunks of 256 (segsum geometry)
#define SEGS 16             // n-segments (decoupled scan)

typedef float f32x4 __attribute__((ext_vector_type(4)));
using s16x8 = __attribute__((ext_vector_type(8))) short;   // 8 bf16 (4 VGPRs)

// Packed partial record: one dwordx3 store/load instead of 3 scattered
// dword ops (R24 scan issued 48 VMEM stores per 16-pt tile — half the
// non-MFMA issue slots).
struct __align__(4) MSP { float m, s, p; };

// alpha in LOG2 units: exp() becomes bare v_exp_f32. Validated R9+.
#define NLOG2E_HALF (-0.72134752044448169f)   // -0.5 * log2(e)

__device__ __forceinline__ float exp2_fast(float x) {
    return __builtin_amdgcn_exp2f(x);
}

// DPP move WITHOUT tied-old operand -> fuses into the consumer op.
template<int CTRL>
__device__ __forceinline__ float dpp_mov_f(float v) {
    return __int_as_float(
        __builtin_amdgcn_mov_dpp(__float_as_int(v), CTRL, 0xF, 0xF, true));
}

// Butterfly reduce over groups of 2^GB lanes (GB = 4 or 6).
template<int GB>
__device__ __forceinline__ float groupMax(float v) {
    v = fmaxf(v, dpp_mov_f<0x0B1>(v));  // xor1
    v = fmaxf(v, dpp_mov_f<0x04E>(v));  // xor2
    v = fmaxf(v, dpp_mov_f<0x141>(v));  // xor4 (row_half_mirror)
    v = fmaxf(v, dpp_mov_f<0x140>(v));  // xor8 (row_mirror)
    if constexpr (GB >= 5) v = fmaxf(v, __shfl_xor(v, 16));
    if constexpr (GB >= 6) v = fmaxf(v, __shfl_xor(v, 32));
    return v;
}

template<int GB>
__device__ __forceinline__ float groupSum(float v) {
    v += dpp_mov_f<0x0B1>(v);
    v += dpp_mov_f<0x04E>(v);
    v += dpp_mov_f<0x141>(v);
    v += dpp_mov_f<0x140>(v);
    if constexpr (GB >= 5) v += __shfl_xor(v, 16);
    if constexpr (GB >= 6) v += __shfl_xor(v, 32);
    return v;
}

// bf16 round-to-nearest-even split: x ~= hi + lo, |x-hi-lo| <= 2^-18 |x|.
__device__ __forceinline__ unsigned short bf16_rne(float x) {
    unsigned u = __float_as_uint(x);
    return (unsigned short)((u + 0x7FFFu + ((u >> 16) & 1u)) >> 16);
}
__device__ __forceinline__ void bf16_split(float x, unsigned short& hi,
                                           unsigned short& lo) {
    const unsigned short h = bf16_rne(x);
    const float xh = __uint_as_float(((unsigned)h) << 16);
    hi = h;
    lo = bf16_rne(x - xh);
}

__device__ __forceinline__ void loadW(const float* __restrict__ W, int col,
                                      f32x4* wv) {
#pragma unroll
    for (int i = 0; i < 16; ++i) {
        wv[i].x = W[(size_t)(4 * i + 0) * TT + col];
        wv[i].y = W[(size_t)(4 * i + 1) * TT + col];
        wv[i].z = W[(size_t)(4 * i + 2) * TT + col];
        wv[i].w = W[(size_t)(4 * i + 3) * TT + col];
    }
}

__device__ __forceinline__ float hsum(f32x4 s) {
    return (s.x + s.y) + (s.z + s.w);
}

// Scalar dot4 (fallback only).
__device__ __forceinline__ void dot4(const float* __restrict__ x0p,
                                     const f32x4* wv, float* xw) {
    const f32x4* xr0 = (const f32x4*)(x0p);
    const f32x4* xr1 = (const f32x4*)(x0p + DD);
    const f32x4* xr2 = (const f32x4*)(x0p + 2 * DD);
    const f32x4* xr3 = (const f32x4*)(x0p + 3 * DD);
    f32x4 s0 = {0.f, 0.f, 0.f, 0.f};
    f32x4 s1 = {0.f, 0.f, 0.f, 0.f};
    f32x4 s2 = {0.f, 0.f, 0.f, 0.f};
    f32x4 s3 = {0.f, 0.f, 0.f, 0.f};
#pragma unroll
    for (int i = 0; i < 16; ++i) {
        const f32x4 w = wv[i];
        s0 += xr0[i] * w;
        s1 += xr1[i] * w;
        s2 += xr2[i] * w;
        s3 += xr3[i] * w;
    }
    xw[0] = hsum(s0); xw[1] = hsum(s1); xw[2] = hsum(s2); xw[3] = hsum(s3);
}

// ---------- split-producing fragment builders (segsum) ----------

__device__ __forceinline__ void loadB64_split(const float* __restrict__ W,
                                              int colbase, int l,
                                              s16x8 bh[2][4], s16x8 bl[2][4],
                                              bool storeW,
                                              unsigned short* __restrict__ whT,
                                              unsigned short* __restrict__ wlT) {
    const int c0  = colbase + (l & 15);
    const int kb0 = (l >> 4) * 8;
#pragma unroll
    for (int ks = 0; ks < 2; ++ks)
#pragma unroll
        for (int nt = 0; nt < 4; ++nt) {
            const int cw = c0 + nt * 16;
#pragma unroll
            for (int j = 0; j < 8; ++j) {
                unsigned short h, lo_;
                bf16_split(W[(size_t)(ks * 32 + kb0 + j) * TT + cw], h, lo_);
                bh[ks][nt][j] = (short)h;
                bl[ks][nt][j] = (short)lo_;
            }
            if (storeW) {
                const size_t off = (size_t)cw * DD + ks * 32 + kb0;
                *(s16x8*)(whT + off) = bh[ks][nt];
                *(s16x8*)(wlT + off) = bl[ks][nt];
            }
        }
}

__device__ __forceinline__ void mfma_tile16_split(const float* __restrict__ xb,
                                                  int tile_n0, int l,
                                                  const s16x8 bh[2][4],
                                                  const s16x8 bl[2][4],
                                                  f32x4 acc[4],
                                                  bool storeX,
                                                  unsigned short* __restrict__ xhB,
                                                  unsigned short* __restrict__ xlB) {
#pragma unroll
    for (int nt = 0; nt < 4; ++nt) acc[nt] = (f32x4){0.f, 0.f, 0.f, 0.f};
    const int row = tile_n0 + (l & 15);
#pragma unroll
    for (int ks = 0; ks < 2; ++ks) {
        const int kb = ks * 32 + (l >> 4) * 8;
        s16x8 ah, al;
#pragma unroll
        for (int j = 0; j < 8; ++j) {
            unsigned short hh, ll;
            bf16_split(xb[(size_t)row * DD + kb + j], hh, ll);
            ah[j] = (short)hh; al[j] = (short)ll;
        }
        if (storeX) {
            const size_t off = (size_t)row * DD + kb;
            *(s16x8*)(xhB + off) = ah;
            *(s16x8*)(xlB + off) = al;
        }
#pragma unroll
        for (int nt = 0; nt < 4; ++nt) {
            acc[nt] = __builtin_amdgcn_mfma_f32_16x16x32_bf16(ah, bh[ks][nt], acc[nt], 0, 0, 0);
            acc[nt] = __builtin_amdgcn_mfma_f32_16x16x32_bf16(ah, bl[ks][nt], acc[nt], 0, 0, 0);
            acc[nt] = __builtin_amdgcn_mfma_f32_16x16x32_bf16(al, bh[ks][nt], acc[nt], 0, 0, 0);
        }
    }
}

// ---------- pre-split fragment loads (scan) ----------

__device__ __forceinline__ void loadB64_pre(const unsigned short* __restrict__ whT,
                                            const unsigned short* __restrict__ wlT,
                                            int colbase, int l,
                                            s16x8 bh[2][4], s16x8 bl[2][4]) {
    const int c0 = colbase + (l & 15);
    const int kb = (l >> 4) * 8;
#pragma unroll
    for (int ks = 0; ks < 2; ++ks)
#pragma unroll
        for (int nt = 0; nt < 4; ++nt) {
            const size_t off = (size_t)(c0 + nt * 16) * DD + ks * 32 + kb;
            bh[ks][nt] = *(const s16x8*)(whT + off);
            bl[ks][nt] = *(const s16x8*)(wlT + off);
        }
}

__device__ __forceinline__ void mfma_tile16_pre(const unsigned short* __restrict__ xh,
                                                const unsigned short* __restrict__ xl,
                                                int tile_n0, int l,
                                                const s16x8 bh[2][4],
                                                const s16x8 bl[2][4],
                                                f32x4 acc[4]) {
#pragma unroll
    for (int nt = 0; nt < 4; ++nt) acc[nt] = (f32x4){0.f, 0.f, 0.f, 0.f};
    const int row = tile_n0 + (l & 15);
#pragma unroll
    for (int ks = 0; ks < 2; ++ks) {
        const size_t off = (size_t)row * DD + ks * 32 + (l >> 4) * 8;
        const s16x8 ah = *(const s16x8*)(xh + off);
        const s16x8 al = *(const s16x8*)(xl + off);
#pragma unroll
        for (int nt = 0; nt < 4; ++nt) {
            acc[nt] = __builtin_amdgcn_mfma_f32_16x16x32_bf16(ah, bh[ks][nt], acc[nt], 0, 0, 0);
            acc[nt] = __builtin_amdgcn_mfma_f32_16x16x32_bf16(ah, bl[ks][nt], acc[nt], 0, 0, 0);
            acc[nt] = __builtin_amdgcn_mfma_f32_16x16x32_bf16(al, bh[ks][nt], acc[nt], 0, 0, 0);
        }
    }
}

// Pass A: MFMA segsum (inline splits) + side-effect split stores (R24).
template<int SEG>
__global__ __launch_bounds__(256)
void segsum_mfma_kernel(const float* __restrict__ data,
                        const float* __restrict__ W,
                        const float* __restrict__ targets,
                        float* __restrict__ segsum,
                        unsigned short* __restrict__ xh,
                        unsigned short* __restrict__ xl,
                        unsigned short* __restrict__ whT,
                        unsigned short* __restrict__ wlT)
{
    constexpr int NSEG = NN / SEG;            // 64
    __shared__ float ts[NSEG];

    const int blk   = blockIdx.x;
    const int s     = blk % SEG;
    const int rem   = blk / SEG;
    const int chunk = rem % CHUNKS;
    const int b     = rem / CHUNKS;
    const int tid   = threadIdx.x;
    const int wv    = tid >> 6;
    const int l     = tid & 63;

    const float* xb = data + (size_t)b * NN * DD;
    const float* tb = targets + (size_t)b * NN;
    const int n0 = s * NSEG;

    if (tid < NSEG) ts[tid] = tb[n0 + tid];

    const bool storeW = (b == 0) && (s == 0);
    const bool storeX = (chunk == 0) && (wv == 0);
    unsigned short* xhB = xh + (size_t)b * NN * DD;
    unsigned short* xlB = xl + (size_t)b * NN * DD;

    s16x8 bh[2][4], bl[2][4];
    loadB64_split(W, chunk * 256 + wv * 64, l, bh, bl, storeW, whT, wlT);
    __syncthreads();

    float colacc[4] = {0.f, 0.f, 0.f, 0.f};

#pragma unroll 1
    for (int h = 0; h < NSEG / 16; ++h) {
        f32x4 acc[4];
        mfma_tile16_split(xb, n0 + h * 16, l, bh, bl, acc, storeX, xhB, xlB);
#pragma unroll
        for (int r = 0; r < 4; ++r) {
            const float tv = ts[h * 16 + (l >> 4) * 4 + r];
#pragma unroll
            for (int nt = 0; nt < 4; ++nt) {
                const float d = tv - acc[nt][r];
                colacc[nt] = fmaf(d * d, NLOG2E_HALF, colacc[nt]);
            }
        }
    }

#pragma unroll
    for (int nt = 0; nt < 4; ++nt) {
        colacc[nt] += __shfl_xor(colacc[nt], 16);
        colacc[nt] += __shfl_xor(colacc[nt], 32);
    }

    if (l < 16) {
        const size_t base = ((size_t)b * SEG + s) * TT + chunk * 256 + wv * 64 + l;
#pragma unroll
        for (int nt = 0; nt < 4; ++nt) segsum[base + nt * 16] = colacc[nt];
    }
}

// Pass B: dual-stream one-wave MFMA scan (R24 structure), packed MSP stores.
template<int SEG, int GB>
__global__ __launch_bounds__(64)
void scan2_mfma_kernel(const unsigned short* __restrict__ xh,
                       const unsigned short* __restrict__ xl,
                       const unsigned short* __restrict__ whT,
                       const unsigned short* __restrict__ wlT,
                       const float* __restrict__ targets,
                       const float* __restrict__ segsum,
                       MSP* __restrict__ msp)
{
    constexpr int NSEG = NN / SEG;            // 64
    constexpr int MT   = 16;
    constexpr int HALF = SEG / 2;             // 8
    constexpr int CG   = TT / 64;             // 32
    constexpr int PPN  = TT >> GB;

    __shared__ __align__(16) float xwA[MT][68];
    __shared__ __align__(16) float xwB[MT][68];

    const int blk = blockIdx.x;
    const int sA  = blk % HALF;
    const int rem = blk / HALF;
    const int cg  = rem % CG;
    const int b   = rem / CG;
    const int sB  = sA + HALF;
    const int l   = threadIdx.x;
    const int col = cg * 64 + l;

    const unsigned short* xbh = xh + (size_t)b * NN * DD;
    const unsigned short* xbl = xl + (size_t)b * NN * DD;
    const float* tb = targets + (size_t)b * NN;

    s16x8 bh[2][4], bl[2][4];
    loadB64_pre(whT, wlT, cg * 64, l, bh, bl);

    const int  k16    = col >> GB;
    const bool writer = (l & ((1 << GB) - 1)) == 0;
    const size_t base0 = (size_t)b * NN * PPN + k16;

    // exclusive segment prefixes for both streams (log2 units)
    float alphaA = 0.0f, alphaB = 0.0f;
    for (int s2 = 0; s2 < sB; ++s2) {
        const float v = segsum[((size_t)b * SEG + s2) * TT + col];
        alphaB += v;
        if (s2 < sA) alphaA += v;
    }

    const int nA0 = sA * NSEG;
    const int nB0 = sB * NSEG;

    auto softmax16 = [&](float& alpha, int nbase, const float (*tile)[68]) {
#pragma unroll 1
        for (int q = 0; q < MT; q += 4) {
            const int n = nbase + q;
            float xw[4];
#pragma unroll
            for (int j = 0; j < 4; ++j) xw[j] = tile[q + j][l];

            float a[4];
            float al_ = alpha;
#pragma unroll
            for (int j = 0; j < 4; ++j) {
                a[j] = al_;
                const float d = tb[n + j] - xw[j];
                al_ = fmaf(d * d, NLOG2E_HALF, al_);
            }
            alpha = al_;

            float m[4], e[4], qv[4], sv[4], pv[4];
#pragma unroll
            for (int j = 0; j < 4; ++j) m[j] = groupMax<GB>(a[j]);
#pragma unroll
            for (int j = 0; j < 4; ++j) {
                e[j]  = exp2_fast(a[j] - m[j]);
                qv[j] = e[j] * xw[j];
            }
#pragma unroll
            for (int j = 0; j < 4; ++j) sv[j] = groupSum<GB>(e[j]);
#pragma unroll
            for (int j = 0; j < 4; ++j) pv[j] = groupSum<GB>(qv[j]);

            if (writer) {
                const size_t i0 = base0 + (size_t)n * PPN;
#pragma unroll
                for (int j = 0; j < 4; ++j) {
                    MSP r; r.m = m[j]; r.s = sv[j]; r.p = pv[j];
                    msp[i0 + (size_t)j * PPN] = r;   // one dwordx3
                }
            }
        }
    };

#pragma unroll 1
    for (int h = 0; h < NSEG / MT; ++h) {
        f32x4 accA[4];
        mfma_tile16_pre(xbh, xbl, nA0 + h * MT, l, bh, bl, accA);
#pragma unroll
        for (int nt = 0; nt < 4; ++nt)
#pragma unroll
            for (int r = 0; r < 4; ++r)
                xwA[(l >> 4) * 4 + r][nt * 16 + (l & 15)] = accA[nt][r];

        f32x4 accB[4];
        mfma_tile16_pre(xbh, xbl, nB0 + h * MT, l, bh, bl, accB);  // overlaps softmax A

        softmax16(alphaA, nA0 + h * MT, xwA);

#pragma unroll
        for (int nt = 0; nt < 4; ++nt)
#pragma unroll
            for (int r = 0; r < 4; ++r)
                xwB[(l >> 4) * 4 + r][nt * 16 + (l & 15)] = accB[nt][r];

        softmax16(alphaB, nB0 + h * MT, xwB);
        // no barriers: single wave, LDS ops program-ordered.
    }
}

// Scalar single-segment scan (fallback only), MSP format.
template<int GB>
__global__ __launch_bounds__(256, 4)
void scan_fallback_kernel(const float* __restrict__ data,
                          const float* __restrict__ targets,
                          const float* __restrict__ W,
                          MSP* __restrict__ msp)
{
    constexpr int PPN = TT >> GB;
    const int blk   = blockIdx.x;
    const int chunk = blk % CHUNKS;
    const int b     = blk / CHUNKS;
    const int tid   = threadIdx.x;
    const int lane  = tid & 63;
    const int col   = chunk * 256 + tid;

    f32x4 wv[16];
    loadW(W, col, wv);

    const float* xb = data + (size_t)b * NN * DD;
    const float* tb = targets + (size_t)b * NN;

    const int  k      = col >> GB;
    const bool writer = (lane & ((1 << GB) - 1)) == 0;
    const size_t base0 = (size_t)b * NN * PPN + k;

    float alpha = 0.0f;
    for (int n = 0; n < NN; n += 4) {
        float xw[4];
        dot4(xb + (size_t)n * DD, wv, xw);
        float a[4];
        float al = alpha;
#pragma unroll
        for (int j = 0; j < 4; ++j) {
            a[j] = al;
            const float d = tb[n + j] - xw[j];
            al = fmaf(d * d, NLOG2E_HALF, al);
        }
        alpha = al;
        float m[4], e[4], qv[4], sv[4], pv[4];
#pragma unroll
        for (int j = 0; j < 4; ++j) m[j] = groupMax<GB>(a[j]);
#pragma unroll
        for (int j = 0; j < 4; ++j) {
            e[j]  = exp2_fast(a[j] - m[j]);
            qv[j] = e[j] * xw[j];
        }
#pragma unroll
        for (int j = 0; j < 4; ++j) sv[j] = groupSum<GB>(e[j]);
#pragma unroll
        for (int j = 0; j < 4; ++j) pv[j] = groupSum<GB>(qv[j]);
        if (writer) {
            const size_t i0 = base0 + (size_t)n * PPN;
#pragma unroll
            for (int j = 0; j < 4; ++j) {
                MSP r; r.m = m[j]; r.s = sv[j]; r.p = pv[j];
                msp[i0 + (size_t)j * PPN] = r;
            }
        }
    }
}

// Pass C: one wave per (b,n): merge PPN packed partials (log2 units).
template<int PPN>
__global__ __launch_bounds__(256)
void combine_kernel(const MSP* __restrict__ msp,
                    float* __restrict__ out)
{
    const int wgid = blockIdx.x * 4 + (threadIdx.x >> 6);   // = b*NN + n
    const int lane = threadIdx.x & 63;
    const size_t base = (size_t)wgid * PPN;

    float m = -INFINITY, s = 0.0f, p = 0.0f;
    if constexpr (PPN >= 64) {
#pragma unroll
        for (int j = 0; j < PPN / 64; ++j) {
            const MSP v = msp[base + lane + j * 64];
            const float M  = fmaxf(m, v.m);
            const float e1 = exp2_fast(m - M), e2 = exp2_fast(v.m - M);
            s = s * e1 + v.s * e2;
            p = p * e1 + v.p * e2;
            m = M;
        }
    } else {
        if (lane < PPN) {
            const MSP v = msp[base + lane];
            m = v.m; s = v.s; p = v.p;
        }
    }

#pragma unroll
    for (int off = 1; off < 64; off <<= 1) {
        const float mo = __shfl_xor(m, off);
        const float so = __shfl_xor(s, off);
        const float po = __shfl_xor(p, off);
        const float M  = fmaxf(m, mo);
        const float e1 = exp2_fast(m - M), e2 = exp2_fast(mo - M);
        s = s * e1 + so * e2;
        p = p * e1 + po * e2;
        m = M;
    }

    if (lane == 0) out[wgid] = p / s;
}

extern "C" void kernel_launch(void* const* d_in, const int* in_sizes, int n_in,
                              void* d_out, int out_size, void* d_ws, size_t ws_size,
                              hipStream_t stream)
{
    (void)in_sizes; (void)n_in; (void)out_size;
    const float* data    = (const float*)d_in[0];
    const float* targets = (const float*)d_in[1];
    const float* W       = (const float*)d_in[2];
    float* out = (float*)d_out;

    const size_t seg16B  = (size_t)BB * SEGS * TT * sizeof(float);     // 4.19 MB
    const size_t xsplitB = (size_t)BB * NN * DD * 2 * 2;               // 8.39 MB (hi+lo)
    const size_t wsplitB = (size_t)TT * DD * 2 * 2;                    // 0.52 MB

    const int seg_grid   = BB * SEGS * CHUNKS;           // 4096 blocks of 256
    const int scan2_grid = BB * (TT / 64) * (SEGS / 2);  // 8192 blocks of 64

    auto launch_pre = [&](auto gbTag) {
        constexpr int GBv = decltype(gbTag)::value;
        constexpr int PPNv = TT >> GBv;
        MSP* msp = (MSP*)d_ws;
        float* sg = (float*)((char*)d_ws + (size_t)BB * NN * PPNv * sizeof(MSP));
        unsigned short* xh  = (unsigned short*)((char*)sg + seg16B);
        unsigned short* xl  = xh + (size_t)BB * NN * DD;
        unsigned short* whT = xl + (size_t)BB * NN * DD;
        unsigned short* wlT = whT + (size_t)TT * DD;

        segsum_mfma_kernel<SEGS><<<seg_grid, 256, 0, stream>>>(
            data, W, targets, sg, xh, xl, whT, wlT);
        scan2_mfma_kernel<SEGS, GBv><<<scan2_grid, 64, 0, stream>>>(
            xh, xl, whT, wlT, targets, sg, msp);
        combine_kernel<PPNv><<<(BB * NN) / 4, 256, 0, stream>>>(msp, out);
    };

    auto needB = [&](int GBv) {
        return (size_t)BB * NN * (TT >> GBv) * sizeof(MSP) + seg16B + xsplitB + wsplitB;
    };

    if (ws_size >= needB(4)) {
        launch_pre(std::integral_constant<int, 4>{});
    } else if (ws_size >= needB(5)) {
        launch_pre(std::integral_constant<int, 5>{});
    } else if (ws_size >= needB(6)) {
        launch_pre(std::integral_constant<int, 6>{});
    } else {
        // minimal fallback: scalar single-segment scan (slow but correct)
        MSP* msp = (MSP*)d_ws;
        scan_fallback_kernel<6><<<BB * CHUNKS, 256, 0, stream>>>(data, targets, W, msp);
        combine_kernel<32><<<(BB * NN) / 4, 256, 0, stream>>>(msp, out);
    }
}